// Round 3
// baseline (1463.968 us; speedup 1.0000x reference)
//
#include <hip/hip_runtime.h>
#include <hip/hip_bf16.h>
#include <cstdint>
#include <cstddef>

// ---------------- problem constants ----------------
#define T_TOK 8192        // B*S tokens
#define DDIM  1024
#define FDIM  4096
#define NEXP  8
#define NSLOT (T_TOK*2)   // 16384 token-expert pairs (top-2)
#define BM    128         // M-tile (slots)
#define MAXTILE 136       // sum ceil(n_e/128) <= 16384/128 + 8

typedef float  f32x4  __attribute__((ext_vector_type(4)));
typedef short  bf16x8 __attribute__((ext_vector_type(8)));
typedef unsigned short u16;

// ---------------- workspace layout (bytes) ----------------
#define XN_OFF   ((size_t)0)                       // T*D bf16      = 16,777,216
#define H_OFF    ((size_t)16777216)                // NSLOT*F bf16  = 134,217,728
#define META     ((size_t)(16777216+134217728))
#define CNT_OFF  (META + 0)                        // 8 int
#define OFF_OFF  (META + 64)                       // 8 int
#define NT_OFF   (META + 128)                      // 1 int
#define TE_OFF   (META + 256)                      // 136 int
#define TS_OFF   (META + 1024)                     // 136 int
#define TR_OFF   (META + 1792)                     // 136 int
#define EK_OFF   (META + 4096)                     // NSLOT int
#define RK_OFF   (EK_OFF + 65536)
#define WK_OFF   (RK_OFF + 65536)
#define PT_OFF   (WK_OFF + 65536)
#define PW_OFF   (PT_OFF + 65536)
// big-path extras: transposed bf16 weights (each 8*4096*1024*2 = 64 MiB)
#define WT1A_OFF ((size_t)152 << 20)
#define WT1B_OFF (WT1A_OFF + ((size_t)64 << 20))
#define WT2_OFF  (WT1B_OFF + ((size_t)64 << 20))
#define WS_BIG   (WT2_OFF  + ((size_t)64 << 20))   // 344 MiB total

__device__ __forceinline__ u16 f2bf(float f) {
    uint32_t x = __float_as_uint(f);
    x += 0x7fffu + ((x >> 16) & 1u);   // round-to-nearest-even
    return (u16)(x >> 16);
}

__device__ __forceinline__ void gload_lds16(const u16* g, u16* l) {
    __builtin_amdgcn_global_load_lds(
        (const __attribute__((address_space(1))) unsigned int*)g,
        (__attribute__((address_space(3))) unsigned int*)l, 16, 0, 0);
}

// ---------------- kernel 1: RMSNorm + gating + top-2 ----------------
__global__ __launch_bounds__(256) void k_rms_gate(
    const float* __restrict__ x, const float* __restrict__ lnw,
    const float* __restrict__ Wg, const float* __restrict__ bg,
    u16* __restrict__ xn, int* __restrict__ counts,
    int* __restrict__ ek, int* __restrict__ rk, float* __restrict__ wk)
{
    const int t = blockIdx.x;
    const int tid = threadIdx.x;
    const int wid = tid >> 6, lane = tid & 63;

    const float4 v = *(const float4*)(x + (size_t)t * DDIM + tid * 4);
    float ss = v.x * v.x + v.y * v.y + v.z * v.z + v.w * v.w;
    #pragma unroll
    for (int o = 32; o; o >>= 1) ss += __shfl_down(ss, o);

    __shared__ float s_red[4];
    __shared__ float s_lg[4][8];
    if (lane == 0) s_red[wid] = ss;
    __syncthreads();
    const float tot = s_red[0] + s_red[1] + s_red[2] + s_red[3];
    const float rms = rsqrtf(tot * (1.0f / DDIM) + 1.1920929e-7f);

    const float4 lw = *(const float4*)(lnw + tid * 4);
    float xv[4] = { v.x * rms * lw.x, v.y * rms * lw.y,
                    v.z * rms * lw.z, v.w * rms * lw.w };
    ushort4 xb;
    xb.x = f2bf(xv[0]); xb.y = f2bf(xv[1]); xb.z = f2bf(xv[2]); xb.w = f2bf(xv[3]);
    *(ushort4*)(xn + (size_t)t * DDIM + tid * 4) = xb;

    // gating logits in fp32 (fp32 xn, pre-bf16-rounding — top-k flip safety)
    float lg[8];
    #pragma unroll
    for (int e = 0; e < 8; e++) lg[e] = 0.f;
    #pragma unroll
    for (int j = 0; j < 4; j++) {
        const float4 g0 = *(const float4*)(Wg + (size_t)(tid * 4 + j) * 8);
        const float4 g1 = *(const float4*)(Wg + (size_t)(tid * 4 + j) * 8 + 4);
        lg[0] += xv[j] * g0.x; lg[1] += xv[j] * g0.y;
        lg[2] += xv[j] * g0.z; lg[3] += xv[j] * g0.w;
        lg[4] += xv[j] * g1.x; lg[5] += xv[j] * g1.y;
        lg[6] += xv[j] * g1.z; lg[7] += xv[j] * g1.w;
    }
    #pragma unroll
    for (int e = 0; e < 8; e++) {
        #pragma unroll
        for (int o = 32; o; o >>= 1) lg[e] += __shfl_down(lg[e], o);
    }
    if (lane == 0) {
        #pragma unroll
        for (int e = 0; e < 8; e++) s_lg[wid][e] = lg[e];
    }
    __syncthreads();
    if (tid == 0) {
        float l[8];
        #pragma unroll
        for (int e = 0; e < 8; e++)
            l[e] = s_lg[0][e] + s_lg[1][e] + s_lg[2][e] + s_lg[3][e] + bg[e];
        int i0 = 0; float v0 = l[0];
        for (int e = 1; e < 8; e++) if (l[e] > v0) { v0 = l[e]; i0 = e; }
        int i1 = -1; float v1 = -3.4e38f;
        for (int e = 0; e < 8; e++) if (e != i0 && l[e] > v1) { v1 = l[e]; i1 = e; }
        const float w0 = 1.f / (1.f + __expf(v1 - v0));
        const float w1 = 1.f - w0;
        const int r0 = atomicAdd(&counts[i0], 1);
        const int r1 = atomicAdd(&counts[i1], 1);
        ek[t * 2]     = i0; rk[t * 2]     = r0; wk[t * 2]     = w0;
        ek[t * 2 + 1] = i1; rk[t * 2 + 1] = r1; wk[t * 2 + 1] = w1;
    }
}

// ---------------- kernel 2: offsets + tile table ----------------
__global__ void k_plan(const int* __restrict__ counts, int* __restrict__ offs,
                       int* __restrict__ ntile, int* __restrict__ tE,
                       int* __restrict__ tS, int* __restrict__ tR)
{
    if (threadIdx.x != 0 || blockIdx.x != 0) return;
    int off = 0, n = 0;
    for (int e = 0; e < NEXP; e++) {
        offs[e] = off;
        const int c = counts[e];
        for (int m = 0; m < c && n < MAXTILE; m += BM) {
            tE[n] = e; tS[n] = off + m; tR[n] = min(BM, c - m); n++;
        }
        off += c;
    }
    *ntile = n;
}

// ---------------- kernel 3: scatter permutation ----------------
__global__ __launch_bounds__(256) void k_scatter(
    const int* __restrict__ ek, const int* __restrict__ rk,
    const float* __restrict__ wk, const int* __restrict__ offs,
    int* __restrict__ pt, float* __restrict__ pw)
{
    const int i = blockIdx.x * 256 + threadIdx.x;
    const int e = ek[i];
    const int slot = offs[e] + rk[i];
    pt[slot] = i >> 1;
    pw[slot] = wk[i];
}

// ---------------- kernel T: fp32 [E][R][C] -> bf16 [E][C][R] transpose ----------------
__global__ __launch_bounds__(256) void k_transpose(
    const float* __restrict__ src, u16* __restrict__ dst, int R, int C)
{
    __shared__ u16 tile[64][72];           // [c][r], padded rows (16B-aligned)
    const int e  = blockIdx.z;
    const int r0 = blockIdx.y * 64;
    const int c0 = blockIdx.x * 64;
    const int t  = threadIdx.x;
    const float* s = src + (size_t)e * R * C;
    u16* d         = dst + (size_t)e * R * C;

    const int lr = t >> 4;                 // 0..15
    const int lc = (t & 15) * 4;           // 0..60
    #pragma unroll
    for (int i = 0; i < 4; i++) {
        const int r = lr + i * 16;
        const float4 v = *(const float4*)(s + (size_t)(r0 + r) * C + c0 + lc);
        tile[lc + 0][r] = f2bf(v.x);
        tile[lc + 1][r] = f2bf(v.y);
        tile[lc + 2][r] = f2bf(v.z);
        tile[lc + 3][r] = f2bf(v.w);
    }
    __syncthreads();
    const int wc = t >> 3;                 // 0..31
    const int wr = (t & 7) * 8;            // 0..56
    #pragma unroll
    for (int i = 0; i < 2; i++) {
        const int c = wc + i * 32;
        const uint4 v = *(const uint4*)&tile[c][wr];
        *(uint4*)(d + (size_t)(c0 + c) * R + r0 + wr) = v;
    }
}

// ---------------- kernel 4T: grouped GEMM1, 128x128-dual tile ----------------
// Per wave per K-step: 32 MFMA : 12 ds_read_b128 : 6 global_load_lds (m97 ratios).
// XCD-chunked swizzle: blocks sharing a W-panel (same f0) land on one XCD's L2.
#define G1_NWG (MAXTILE * (FDIM / 128))    // 136*32 = 4352, %8==0
__global__ __launch_bounds__(256, 2) void k_gemm1_t(
    const u16* __restrict__ xn, const int* __restrict__ pt, const float* __restrict__ pw,
    const u16* __restrict__ wt1a, const float* __restrict__ b1a,
    const u16* __restrict__ wt1b, const float* __restrict__ b1b,
    const int* __restrict__ ntile, const int* __restrict__ tE,
    const int* __restrict__ tS, const int* __restrict__ tR,
    u16* __restrict__ h)
{
    // bijective chunked XCD swizzle (T1): work = (hw%8)*(NWG/8) + hw/8
    const int hw   = blockIdx.y * MAXTILE + blockIdx.x;
    const int work = (hw & 7) * (G1_NWG / 8) + (hw >> 3);
    const int bx   = work % MAXTILE;
    const int f0   = (work / MAXTILE) * 128;

    if (bx >= *ntile) return;
    const int e = tE[bx], slot0 = tS[bx], rows = tR[bx];
    const int tid = threadIdx.x;

    __shared__ u16 lds[3 * 128 * 32];      // A 8KB | Wa 8KB | Wb 8KB, linear
    u16* ldsA  = lds;
    u16* ldsWa = lds + 128 * 32;
    u16* ldsWb = lds + 2 * 128 * 32;

    // staging map: thread t -> (row = t>>2 [+64], 16B-chunk = t&3); LDS dest linear
    const int rA = tid >> 2, cA = tid & 3;
    const int tok0 = pt[slot0 + min(rA,      rows - 1)];
    const int tok1 = pt[slot0 + min(rA + 64, rows - 1)];
    const u16* gA0  = xn + (size_t)tok0 * DDIM + cA * 8;
    const u16* gA1  = xn + (size_t)tok1 * DDIM + cA * 8;
    const u16* gWa0 = wt1a + ((size_t)e * FDIM + f0 + rA) * DDIM + cA * 8;
    const u16* gWa1 = gWa0 + (size_t)64 * DDIM;
    const u16* gWb0 = wt1b + ((size_t)e * FDIM + f0 + rA) * DDIM + cA * 8;
    const u16* gWb1 = gWb0 + (size_t)64 * DDIM;
    u16* dA0  = ldsA  + tid * 8;
    u16* dA1  = ldsA  + 2048 + tid * 8;
    u16* dWa0 = ldsWa + tid * 8;
    u16* dWa1 = ldsWa + 2048 + tid * 8;
    u16* dWb0 = ldsWb + tid * 8;
    u16* dWb1 = ldsWb + 2048 + tid * 8;

    const int wid = tid >> 6, lane = tid & 63;
    const int wm = wid & 1, wn = wid >> 1;        // wave tile: 64m x 64f (per matrix)
    const int ln = lane & 15, q = lane >> 4;

    f32x4 accA[4][4], accB[4][4];
    #pragma unroll
    for (int i = 0; i < 4; i++)
        #pragma unroll
        for (int j = 0; j < 4; j++) {
            accA[i][j] = (f32x4){0.f, 0.f, 0.f, 0.f};
            accB[i][j] = (f32x4){0.f, 0.f, 0.f, 0.f};
        }

    for (int k0 = 0; k0 < DDIM; k0 += 32) {
        __syncthreads();                           // all waves done reading prev tile
        gload_lds16(gA0  + k0, dA0);
        gload_lds16(gA1  + k0, dA1);
        gload_lds16(gWa0 + k0, dWa0);
        gload_lds16(gWa1 + k0, dWa1);
        gload_lds16(gWb0 + k0, dWb0);
        gload_lds16(gWb1 + k0, dWb1);
        __syncthreads();                           // drains vmcnt -> tile ready

        bf16x8 af[4], ba[4], bb[4];
        #pragma unroll
        for (int i = 0; i < 4; i++)
            af[i] = *(const bf16x8*)(ldsA + (wm * 64 + i * 16 + ln) * 32 + q * 8);
        #pragma unroll
        for (int j = 0; j < 4; j++) {
            ba[j] = *(const bf16x8*)(ldsWa + (wn * 64 + j * 16 + ln) * 32 + q * 8);
            bb[j] = *(const bf16x8*)(ldsWb + (wn * 64 + j * 16 + ln) * 32 + q * 8);
        }
        #pragma unroll
        for (int i = 0; i < 4; i++)
            #pragma unroll
            for (int j = 0; j < 4; j++) {
                accA[i][j] = __builtin_amdgcn_mfma_f32_16x16x32_bf16(af[i], ba[j], accA[i][j], 0, 0, 0);
                accB[i][j] = __builtin_amdgcn_mfma_f32_16x16x32_bf16(af[i], bb[j], accB[i][j], 0, 0, 0);
            }
    }

    // epilogue: h = gate_w * silu(a + b1a) * (b + b1b), stored bf16
    #pragma unroll
    for (int i = 0; i < 4; i++) {
        const int mb = wm * 64 + i * 16 + q * 4;
        #pragma unroll
        for (int j = 0; j < 4; j++) {
            const int fg = f0 + wn * 64 + j * 16 + ln;
            const float bav = b1a[e * FDIM + fg];
            const float bbv = b1b[e * FDIM + fg];
            #pragma unroll
            for (int r = 0; r < 4; r++) {
                const int m = mb + r;
                if (m < rows) {
                    const float a = accA[i][j][r] + bav;
                    const float b = accB[i][j][r] + bbv;
                    const float s = a / (1.f + __expf(-a));
                    const float hv = pw[slot0 + m] * s * b;
                    h[(size_t)(slot0 + m) * FDIM + fg] = f2bf(hv);
                }
            }
        }
    }
}

// ---------------- kernel 5T: grouped GEMM2, 128x256 tile + atomic scatter-add ----
#define G2_NWG (MAXTILE * (DDIM / 256))    // 136*4 = 544, %8==0
__global__ __launch_bounds__(256, 2) void k_gemm2_t(
    const u16* __restrict__ h, const int* __restrict__ pt, const float* __restrict__ pw,
    const u16* __restrict__ wt2, const float* __restrict__ b2,
    const int* __restrict__ ntile, const int* __restrict__ tE,
    const int* __restrict__ tS, const int* __restrict__ tR,
    float* __restrict__ out)
{
    const int hw   = blockIdx.y * MAXTILE + blockIdx.x;
    const int work = (hw & 7) * (G2_NWG / 8) + (hw >> 3);
    const int bx   = work % MAXTILE;
    const int n0   = (work / MAXTILE) * 256;

    if (bx >= *ntile) return;
    const int e = tE[bx], slot0 = tS[bx], rows = tR[bx];
    const int tid = threadIdx.x;

    __shared__ u16 lds[128 * 32 + 256 * 32];      // A 8KB | W 16KB, linear
    u16* ldsA = lds;
    u16* ldsW = lds + 128 * 32;

    const int rA = tid >> 2, cA = tid & 3;
    const int r0c = min(rA,      rows - 1);
    const int r1c = min(rA + 64, rows - 1);
    const u16* gA0 = h + (size_t)(slot0 + r0c) * FDIM + cA * 8;
    const u16* gA1 = h + (size_t)(slot0 + r1c) * FDIM + cA * 8;
    const u16* gW0 = wt2 + ((size_t)e * DDIM + n0 + rA)       * FDIM + cA * 8;
    const u16* gW1 = gW0 + (size_t)64  * FDIM;
    const u16* gW2 = gW0 + (size_t)128 * FDIM;
    const u16* gW3 = gW0 + (size_t)192 * FDIM;
    u16* dA0 = ldsA + tid * 8;
    u16* dA1 = ldsA + 2048 + tid * 8;
    u16* dW0 = ldsW + tid * 8;
    u16* dW1 = ldsW + 2048 + tid * 8;
    u16* dW2 = ldsW + 4096 + tid * 8;
    u16* dW3 = ldsW + 6144 + tid * 8;

    const int wid = tid >> 6, lane = tid & 63;
    const int wm = wid & 1, wn = wid >> 1;        // wave tile: 64m x 128n
    const int ln = lane & 15, q = lane >> 4;

    f32x4 acc[4][8];
    #pragma unroll
    for (int i = 0; i < 4; i++)
        #pragma unroll
        for (int j = 0; j < 8; j++) acc[i][j] = (f32x4){0.f, 0.f, 0.f, 0.f};

    for (int k0 = 0; k0 < FDIM; k0 += 32) {
        __syncthreads();
        gload_lds16(gA0 + k0, dA0);
        gload_lds16(gA1 + k0, dA1);
        gload_lds16(gW0 + k0, dW0);
        gload_lds16(gW1 + k0, dW1);
        gload_lds16(gW2 + k0, dW2);
        gload_lds16(gW3 + k0, dW3);
        __syncthreads();

        bf16x8 af[4], bf[8];
        #pragma unroll
        for (int i = 0; i < 4; i++)
            af[i] = *(const bf16x8*)(ldsA + (wm * 64 + i * 16 + ln) * 32 + q * 8);
        #pragma unroll
        for (int j = 0; j < 8; j++)
            bf[j] = *(const bf16x8*)(ldsW + (wn * 128 + j * 16 + ln) * 32 + q * 8);
        #pragma unroll
        for (int i = 0; i < 4; i++)
            #pragma unroll
            for (int j = 0; j < 8; j++)
                acc[i][j] = __builtin_amdgcn_mfma_f32_16x16x32_bf16(af[i], bf[j], acc[i][j], 0, 0, 0);
    }

    #pragma unroll
    for (int i = 0; i < 4; i++) {
        const int mb = wm * 64 + i * 16 + q * 4;
        #pragma unroll
        for (int j = 0; j < 8; j++) {
            const int d = n0 + wn * 128 + j * 16 + ln;
            const float b2v = b2[e * DDIM + d];
            #pragma unroll
            for (int r = 0; r < 4; r++) {
                const int m = mb + r;
                if (m < rows) {
                    const int slot = slot0 + m;
                    const int tok = pt[slot];
                    const float val = acc[i][j][r] + pw[slot] * b2v;
                    atomicAdd(out + (size_t)tok * DDIM + d, val);
                }
            }
        }
    }
}

// ================= FALLBACK PATH (verified baseline, unchanged) =================

__global__ __launch_bounds__(256, 2) void k_gemm1(
    const u16* __restrict__ xn, const int* __restrict__ pt, const float* __restrict__ pw,
    const float* __restrict__ W1a, const float* __restrict__ b1a,
    const float* __restrict__ W1b, const float* __restrict__ b1b,
    const int* __restrict__ ntile, const int* __restrict__ tE,
    const int* __restrict__ tS, const int* __restrict__ tR,
    u16* __restrict__ h)
{
    const int bx = blockIdx.x;
    if (bx >= *ntile) return;
    const int e = tE[bx], slot0 = tS[bx], rows = tR[bx];
    const int f0 = blockIdx.y * 128;
    const int tid = threadIdx.x;

    __shared__ u16 lds[3 * 128 * 40];
    u16* ldsA  = lds;
    u16* ldsWa = lds + 128 * 40;
    u16* ldsWb = lds + 2 * 128 * 40;

    const int ar = tid >> 1, ah = tid & 1;
    const int tok = pt[slot0 + min(ar, rows - 1)];
    const u16* aptr = xn + (size_t)tok * DDIM + ah * 16;

    const int fq = tid & 31, dq = tid >> 5;
    const float* wa_base = W1a + (size_t)e * DDIM * FDIM + (f0 + fq * 4);
    const float* wb_base = W1b + (size_t)e * DDIM * FDIM + (f0 + fq * 4);

    const int wid = tid >> 6, lane = tid & 63;
    const int wm = wid & 1, wn = wid >> 1;
    const int ln = lane & 15, q = lane >> 4;

    f32x4 accA[4][4], accB[4][4];
    #pragma unroll
    for (int i = 0; i < 4; i++)
        #pragma unroll
        for (int j = 0; j < 4; j++) {
            accA[i][j] = (f32x4){0.f, 0.f, 0.f, 0.f};
            accB[i][j] = (f32x4){0.f, 0.f, 0.f, 0.f};
        }

    for (int k0 = 0; k0 < DDIM; k0 += 32) {
        const uint4 av0 = *(const uint4*)(aptr + k0);
        const uint4 av1 = *(const uint4*)(aptr + k0 + 8);
        float4 wa[4], wb[4];
        #pragma unroll
        for (int i = 0; i < 4; i++) {
            wa[i] = *(const float4*)(wa_base + (size_t)(k0 + dq * 4 + i) * FDIM);
            wb[i] = *(const float4*)(wb_base + (size_t)(k0 + dq * 4 + i) * FDIM);
        }
        __syncthreads();
        *(uint4*)(ldsA + ar * 40 + ah * 16)     = av0;
        *(uint4*)(ldsA + ar * 40 + ah * 16 + 8) = av1;
        #pragma unroll
        for (int j = 0; j < 4; j++) {
            ushort4 pa, pb;
            pa.x = f2bf(((const float*)&wa[0])[j]); pa.y = f2bf(((const float*)&wa[1])[j]);
            pa.z = f2bf(((const float*)&wa[2])[j]); pa.w = f2bf(((const float*)&wa[3])[j]);
            pb.x = f2bf(((const float*)&wb[0])[j]); pb.y = f2bf(((const float*)&wb[1])[j]);
            pb.z = f2bf(((const float*)&wb[2])[j]); pb.w = f2bf(((const float*)&wb[3])[j]);
            *(ushort4*)(ldsWa + (fq * 4 + j) * 40 + dq * 4) = pa;
            *(ushort4*)(ldsWb + (fq * 4 + j) * 40 + dq * 4) = pb;
        }
        __syncthreads();
        bf16x8 af[4], ba[4], bb[4];
        #pragma unroll
        for (int i = 0; i < 4; i++)
            af[i] = *(const bf16x8*)(ldsA + (wm * 64 + i * 16 + ln) * 40 + q * 8);
        #pragma unroll
        for (int j = 0; j < 4; j++) {
            ba[j] = *(const bf16x8*)(ldsWa + (wn * 64 + j * 16 + ln) * 40 + q * 8);
            bb[j] = *(const bf16x8*)(ldsWb + (wn * 64 + j * 16 + ln) * 40 + q * 8);
        }
        #pragma unroll
        for (int i = 0; i < 4; i++)
            #pragma unroll
            for (int j = 0; j < 4; j++) {
                accA[i][j] = __builtin_amdgcn_mfma_f32_16x16x32_bf16(af[i], ba[j], accA[i][j], 0, 0, 0);
                accB[i][j] = __builtin_amdgcn_mfma_f32_16x16x32_bf16(af[i], bb[j], accB[i][j], 0, 0, 0);
            }
    }

    #pragma unroll
    for (int i = 0; i < 4; i++) {
        const int mb = wm * 64 + i * 16 + q * 4;
        #pragma unroll
        for (int j = 0; j < 4; j++) {
            const int fg = f0 + wn * 64 + j * 16 + ln;
            const float bav = b1a[e * FDIM + fg];
            const float bbv = b1b[e * FDIM + fg];
            #pragma unroll
            for (int r = 0; r < 4; r++) {
                const int m = mb + r;
                if (m < rows) {
                    const float a = accA[i][j][r] + bav;
                    const float b = accB[i][j][r] + bbv;
                    const float s = a / (1.f + __expf(-a));
                    const float hv = pw[slot0 + m] * s * b;
                    h[(size_t)(slot0 + m) * FDIM + fg] = f2bf(hv);
                }
            }
        }
    }
}

__global__ __launch_bounds__(256, 2) void k_gemm2(
    const u16* __restrict__ h, const int* __restrict__ pt, const float* __restrict__ pw,
    const float* __restrict__ W2, const float* __restrict__ b2,
    const int* __restrict__ ntile, const int* __restrict__ tE,
    const int* __restrict__ tS, const int* __restrict__ tR,
    float* __restrict__ out)
{
    const int bx = blockIdx.x;
    if (bx >= *ntile) return;
    const int e = tE[bx], slot0 = tS[bx], rows = tR[bx];
    const int n0 = blockIdx.y * 128;
    const int tid = threadIdx.x;

    __shared__ u16 lds[2 * 128 * 40];
    u16* ldsA = lds;
    u16* ldsW = lds + 128 * 40;

    const int ar = tid >> 1, ah = tid & 1;
    const int arc = min(ar, rows - 1);
    const u16* aptr = h + (size_t)(slot0 + arc) * FDIM + ah * 16;

    const int fq = tid & 31, dq = tid >> 5;
    const float* w_base = W2 + (size_t)e * FDIM * DDIM + (n0 + fq * 4);

    const int wid = tid >> 6, lane = tid & 63;
    const int wm = wid & 1, wn = wid >> 1;
    const int ln = lane & 15, q = lane >> 4;

    f32x4 acc[4][4];
    #pragma unroll
    for (int i = 0; i < 4; i++)
        #pragma unroll
        for (int j = 0; j < 4; j++) acc[i][j] = (f32x4){0.f, 0.f, 0.f, 0.f};

    for (int k0 = 0; k0 < FDIM; k0 += 32) {
        const uint4 av0 = *(const uint4*)(aptr + k0);
        const uint4 av1 = *(const uint4*)(aptr + k0 + 8);
        float4 wv[4];
        #pragma unroll
        for (int i = 0; i < 4; i++)
            wv[i] = *(const float4*)(w_base + (size_t)(k0 + dq * 4 + i) * DDIM);
        __syncthreads();
        *(uint4*)(ldsA + ar * 40 + ah * 16)     = av0;
        *(uint4*)(ldsA + ar * 40 + ah * 16 + 8) = av1;
        #pragma unroll
        for (int j = 0; j < 4; j++) {
            ushort4 p;
            p.x = f2bf(((const float*)&wv[0])[j]); p.y = f2bf(((const float*)&wv[1])[j]);
            p.z = f2bf(((const float*)&wv[2])[j]); p.w = f2bf(((const float*)&wv[3])[j]);
            *(ushort4*)(ldsW + (fq * 4 + j) * 40 + dq * 4) = p;
        }
        __syncthreads();
        bf16x8 af[4], bf[4];
        #pragma unroll
        for (int i = 0; i < 4; i++)
            af[i] = *(const bf16x8*)(ldsA + (wm * 64 + i * 16 + ln) * 40 + q * 8);
        #pragma unroll
        for (int j = 0; j < 4; j++)
            bf[j] = *(const bf16x8*)(ldsW + (wn * 64 + j * 16 + ln) * 40 + q * 8);
        #pragma unroll
        for (int i = 0; i < 4; i++)
            #pragma unroll
            for (int j = 0; j < 4; j++)
                acc[i][j] = __builtin_amdgcn_mfma_f32_16x16x32_bf16(af[i], bf[j], acc[i][j], 0, 0, 0);
    }

    #pragma unroll
    for (int i = 0; i < 4; i++) {
        const int mb = wm * 64 + i * 16 + q * 4;
        #pragma unroll
        for (int j = 0; j < 4; j++) {
            const int d = n0 + wn * 64 + j * 16 + ln;
            const float b2v = b2[e * DDIM + d];
            #pragma unroll
            for (int r = 0; r < 4; r++) {
                const int m = mb + r;
                if (m < rows) {
                    const int slot = slot0 + m;
                    const int tok = pt[slot];
                    const float val = acc[i][j][r] + pw[slot] * b2v;
                    atomicAdd(out + (size_t)tok * DDIM + d, val);
                }
            }
        }
    }
}

// ---------------- launch ----------------
extern "C" void kernel_launch(void* const* d_in, const int* in_sizes, int n_in,
                              void* d_out, int out_size, void* d_ws, size_t ws_size,
                              hipStream_t stream)
{
    (void)in_sizes; (void)n_in; (void)out_size;
    const float* x   = (const float*)d_in[0];
    const float* lnw = (const float*)d_in[1];
    const float* Wg  = (const float*)d_in[2];
    const float* bg  = (const float*)d_in[3];
    const float* W1a = (const float*)d_in[4];
    const float* b1a = (const float*)d_in[5];
    const float* W1b = (const float*)d_in[6];
    const float* b1b = (const float*)d_in[7];
    const float* W2  = (const float*)d_in[8];
    const float* b2  = (const float*)d_in[9];
    float* out = (float*)d_out;
    char* ws = (char*)d_ws;

    u16*   xn     = (u16*)(ws + XN_OFF);
    u16*   h      = (u16*)(ws + H_OFF);
    int*   counts = (int*)(ws + CNT_OFF);
    int*   offs   = (int*)(ws + OFF_OFF);
    int*   ntile  = (int*)(ws + NT_OFF);
    int*   tE     = (int*)(ws + TE_OFF);
    int*   tS     = (int*)(ws + TS_OFF);
    int*   tR     = (int*)(ws + TR_OFF);
    int*   ek     = (int*)(ws + EK_OFF);
    int*   rk     = (int*)(ws + RK_OFF);
    float* wk     = (float*)(ws + WK_OFF);
    int*   pt     = (int*)(ws + PT_OFF);
    float* pw     = (float*)(ws + PW_OFF);

    hipMemsetAsync(counts, 0, 32, stream);
    hipMemsetAsync(out, 0, (size_t)T_TOK * DDIM * sizeof(float), stream);

    const bool big = (ws_size >= WS_BIG);

    if (big) {
        u16* wt1a = (u16*)(ws + WT1A_OFF);
        u16* wt1b = (u16*)(ws + WT1B_OFF);
        u16* wt2  = (u16*)(ws + WT2_OFF);

        // weight transpose+convert: W1 [E][D][F]->[E][F][D], W2 [E][F][D]->[E][D][F]
        k_transpose<<<dim3(FDIM / 64, DDIM / 64, NEXP), 256, 0, stream>>>(W1a, wt1a, DDIM, FDIM);
        k_transpose<<<dim3(FDIM / 64, DDIM / 64, NEXP), 256, 0, stream>>>(W1b, wt1b, DDIM, FDIM);
        k_transpose<<<dim3(DDIM / 64, FDIM / 64, NEXP), 256, 0, stream>>>(W2,  wt2,  FDIM, DDIM);

        k_rms_gate<<<T_TOK, 256, 0, stream>>>(x, lnw, Wg, bg, xn, counts, ek, rk, wk);
        k_plan<<<1, 1, 0, stream>>>(counts, offs, ntile, tE, tS, tR);
        k_scatter<<<NSLOT / 256, 256, 0, stream>>>(ek, rk, wk, offs, pt, pw);

        dim3 g1(MAXTILE, FDIM / 128);
        k_gemm1_t<<<g1, 256, 0, stream>>>(xn, pt, pw, wt1a, b1a, wt1b, b1b,
                                          ntile, tE, tS, tR, h);
        dim3 g2(MAXTILE, DDIM / 256);
        k_gemm2_t<<<g2, 256, 0, stream>>>(h, pt, pw, wt2, b2,
                                          ntile, tE, tS, tR, out);
    } else {
        // fallback: verified baseline path (workspace too small for bf16 W^T)
        k_rms_gate<<<T_TOK, 256, 0, stream>>>(x, lnw, Wg, bg, xn, counts, ek, rk, wk);
        k_plan<<<1, 1, 0, stream>>>(counts, offs, ntile, tE, tS, tR);
        k_scatter<<<NSLOT / 256, 256, 0, stream>>>(ek, rk, wk, offs, pt, pw);

        dim3 g1(MAXTILE, FDIM / 128);
        k_gemm1<<<g1, 256, 0, stream>>>(xn, pt, pw, W1a, b1a, W1b, b1b,
                                        ntile, tE, tS, tR, h);
        dim3 g2(MAXTILE, DDIM / 128);
        k_gemm2<<<g2, 256, 0, stream>>>(h, pt, pw, W2, b2,
                                        ntile, tE, tS, tR, out);
    }
}

// Round 5
// 1253.007 us; speedup vs baseline: 1.1684x; 1.1684x over previous
//
#include <hip/hip_runtime.h>
#include <hip/hip_bf16.h>
#include <cstdint>
#include <cstddef>

// ---------------- problem constants ----------------
#define T_TOK 8192        // B*S tokens
#define DDIM  1024
#define FDIM  4096
#define NEXP  8
#define NSLOT (T_TOK*2)   // 16384 token-expert pairs (top-2)
#define BM    128         // M-tile (slots)
#define MAXTILE 136       // sum ceil(n_e/128) <= 16384/128 + 8

typedef float  f32x4  __attribute__((ext_vector_type(4)));
typedef short  bf16x8 __attribute__((ext_vector_type(8)));
typedef unsigned short u16;

// ---------------- workspace layout (bytes) ----------------
#define XN_OFF   ((size_t)0)                       // T*D bf16      = 16,777,216
#define H_OFF    ((size_t)16777216)                // NSLOT*F bf16  = 134,217,728
#define META     ((size_t)(16777216+134217728))
#define CNT_OFF  (META + 0)                        // 8 int
#define OFF_OFF  (META + 64)                       // 8 int
#define NT_OFF   (META + 128)                      // 1 int
#define TE_OFF   (META + 256)                      // 136 int
#define TS_OFF   (META + 1024)                     // 136 int
#define TR_OFF   (META + 1792)                     // 136 int
#define EK_OFF   (META + 4096)                     // NSLOT int
#define RK_OFF   (EK_OFF + 65536)
#define WK_OFF   (RK_OFF + 65536)
#define PT_OFF   (WK_OFF + 65536)
#define PW_OFF   (PT_OFF + 65536)
// big-path extras: transposed bf16 weights (each 8*4096*1024*2 = 64 MiB)
#define WT1A_OFF ((size_t)152 << 20)
#define WT1B_OFF (WT1A_OFF + ((size_t)64 << 20))
#define WT2_OFF  (WT1B_OFF + ((size_t)64 << 20))
#define WS_BIG   (WT2_OFF  + ((size_t)64 << 20))   // 344 MiB total

__device__ __forceinline__ u16 f2bf(float f) {
    uint32_t x = __float_as_uint(f);
    x += 0x7fffu + ((x >> 16) & 1u);   // round-to-nearest-even
    return (u16)(x >> 16);
}

__device__ __forceinline__ void gload_lds16(const u16* g, u16* l) {
    __builtin_amdgcn_global_load_lds(
        (const __attribute__((address_space(1))) unsigned int*)g,
        (__attribute__((address_space(3))) unsigned int*)l, 16, 0, 0);
}

// ---------------- kernel 1: RMSNorm + gating + top-2 ----------------
__global__ __launch_bounds__(256) void k_rms_gate(
    const float* __restrict__ x, const float* __restrict__ lnw,
    const float* __restrict__ Wg, const float* __restrict__ bg,
    u16* __restrict__ xn, int* __restrict__ counts,
    int* __restrict__ ek, int* __restrict__ rk, float* __restrict__ wk)
{
    const int t = blockIdx.x;
    const int tid = threadIdx.x;
    const int wid = tid >> 6, lane = tid & 63;

    const float4 v = *(const float4*)(x + (size_t)t * DDIM + tid * 4);
    float ss = v.x * v.x + v.y * v.y + v.z * v.z + v.w * v.w;
    #pragma unroll
    for (int o = 32; o; o >>= 1) ss += __shfl_down(ss, o);

    __shared__ float s_red[4];
    __shared__ float s_lg[4][8];
    if (lane == 0) s_red[wid] = ss;
    __syncthreads();
    const float tot = s_red[0] + s_red[1] + s_red[2] + s_red[3];
    const float rms = rsqrtf(tot * (1.0f / DDIM) + 1.1920929e-7f);

    const float4 lw = *(const float4*)(lnw + tid * 4);
    float xv[4] = { v.x * rms * lw.x, v.y * rms * lw.y,
                    v.z * rms * lw.z, v.w * rms * lw.w };
    ushort4 xb;
    xb.x = f2bf(xv[0]); xb.y = f2bf(xv[1]); xb.z = f2bf(xv[2]); xb.w = f2bf(xv[3]);
    *(ushort4*)(xn + (size_t)t * DDIM + tid * 4) = xb;

    // gating logits in fp32 (fp32 xn, pre-bf16-rounding — top-k flip safety)
    float lg[8];
    #pragma unroll
    for (int e = 0; e < 8; e++) lg[e] = 0.f;
    #pragma unroll
    for (int j = 0; j < 4; j++) {
        const float4 g0 = *(const float4*)(Wg + (size_t)(tid * 4 + j) * 8);
        const float4 g1 = *(const float4*)(Wg + (size_t)(tid * 4 + j) * 8 + 4);
        lg[0] += xv[j] * g0.x; lg[1] += xv[j] * g0.y;
        lg[2] += xv[j] * g0.z; lg[3] += xv[j] * g0.w;
        lg[4] += xv[j] * g1.x; lg[5] += xv[j] * g1.y;
        lg[6] += xv[j] * g1.z; lg[7] += xv[j] * g1.w;
    }
    #pragma unroll
    for (int e = 0; e < 8; e++) {
        #pragma unroll
        for (int o = 32; o; o >>= 1) lg[e] += __shfl_down(lg[e], o);
    }
    if (lane == 0) {
        #pragma unroll
        for (int e = 0; e < 8; e++) s_lg[wid][e] = lg[e];
    }
    __syncthreads();
    if (tid == 0) {
        float l[8];
        #pragma unroll
        for (int e = 0; e < 8; e++)
            l[e] = s_lg[0][e] + s_lg[1][e] + s_lg[2][e] + s_lg[3][e] + bg[e];
        int i0 = 0; float v0 = l[0];
        for (int e = 1; e < 8; e++) if (l[e] > v0) { v0 = l[e]; i0 = e; }
        int i1 = -1; float v1 = -3.4e38f;
        for (int e = 0; e < 8; e++) if (e != i0 && l[e] > v1) { v1 = l[e]; i1 = e; }
        const float w0 = 1.f / (1.f + __expf(v1 - v0));
        const float w1 = 1.f - w0;
        const int r0 = atomicAdd(&counts[i0], 1);
        const int r1 = atomicAdd(&counts[i1], 1);
        ek[t * 2]     = i0; rk[t * 2]     = r0; wk[t * 2]     = w0;
        ek[t * 2 + 1] = i1; rk[t * 2 + 1] = r1; wk[t * 2 + 1] = w1;
    }
}

// ---------------- kernel 2: offsets + tile table ----------------
__global__ void k_plan(const int* __restrict__ counts, int* __restrict__ offs,
                       int* __restrict__ ntile, int* __restrict__ tE,
                       int* __restrict__ tS, int* __restrict__ tR)
{
    if (threadIdx.x != 0 || blockIdx.x != 0) return;
    int off = 0, n = 0;
    for (int e = 0; e < NEXP; e++) {
        offs[e] = off;
        const int c = counts[e];
        for (int m = 0; m < c && n < MAXTILE; m += BM) {
            tE[n] = e; tS[n] = off + m; tR[n] = min(BM, c - m); n++;
        }
        off += c;
    }
    *ntile = n;
}

// ---------------- kernel 3: scatter permutation ----------------
__global__ __launch_bounds__(256) void k_scatter(
    const int* __restrict__ ek, const int* __restrict__ rk,
    const float* __restrict__ wk, const int* __restrict__ offs,
    int* __restrict__ pt, float* __restrict__ pw)
{
    const int i = blockIdx.x * 256 + threadIdx.x;
    const int e = ek[i];
    const int slot = offs[e] + rk[i];
    pt[slot] = i >> 1;
    pw[slot] = wk[i];
}

// ---------------- kernel T: fp32 [E][R][C] -> bf16 [E][C][R] transpose ----------------
__global__ __launch_bounds__(256) void k_transpose(
    const float* __restrict__ src, u16* __restrict__ dst, int R, int C)
{
    __shared__ u16 tile[64][72];           // [c][r], padded rows (16B-aligned)
    const int e  = blockIdx.z;
    const int r0 = blockIdx.y * 64;
    const int c0 = blockIdx.x * 64;
    const int t  = threadIdx.x;
    const float* s = src + (size_t)e * R * C;
    u16* d         = dst + (size_t)e * R * C;

    const int lr = t >> 4;                 // 0..15
    const int lc = (t & 15) * 4;           // 0..60
    #pragma unroll
    for (int i = 0; i < 4; i++) {
        const int r = lr + i * 16;
        const float4 v = *(const float4*)(s + (size_t)(r0 + r) * C + c0 + lc);
        tile[lc + 0][r] = f2bf(v.x);
        tile[lc + 1][r] = f2bf(v.y);
        tile[lc + 2][r] = f2bf(v.z);
        tile[lc + 3][r] = f2bf(v.w);
    }
    __syncthreads();
    const int wc = t >> 3;                 // 0..31
    const int wr = (t & 7) * 8;            // 0..56
    #pragma unroll
    for (int i = 0; i < 2; i++) {
        const int c = wc + i * 32;
        const uint4 v = *(const uint4*)&tile[c][wr];
        *(uint4*)(d + (size_t)(c0 + c) * R + r0 + wr) = v;
    }
}

// ---------------- kernel 4T: grouped GEMM1, 128x64-dual tile, BK=64 ----------------
// Round-2 geometry (occupancy-proven: 43%) with BK=64 stored as TWO BK=32
// sub-tiles (round-2 LDS layout + s*subtile offset). Halves barrier count;
// 8 gloads in flight per drain instead of 4.
#define G1_NWG (MAXTILE * (FDIM / 64))     // 136*64 = 8704, %8==0
__global__ __launch_bounds__(256, 2) void k_gemm1_t(
    const u16* __restrict__ xn, const int* __restrict__ pt, const float* __restrict__ pw,
    const u16* __restrict__ wt1a, const float* __restrict__ b1a,
    const u16* __restrict__ wt1b, const float* __restrict__ b1b,
    const int* __restrict__ ntile, const int* __restrict__ tE,
    const int* __restrict__ tS, const int* __restrict__ tR,
    u16* __restrict__ h)
{
    // bijective chunked XCD swizzle (T1)
    const int hw   = blockIdx.y * MAXTILE + blockIdx.x;
    const int work = (hw & 7) * (G1_NWG / 8) + (hw >> 3);
    const int bx   = work % MAXTILE;
    const int f0   = (work / MAXTILE) * 64;

    if (bx >= *ntile) return;
    const int e = tE[bx], slot0 = tS[bx], rows = tR[bx];
    const int tid = threadIdx.x;

    __shared__ u16 lds[128 * 64 + 2 * 64 * 64];   // A 16KB | Wa 8KB | Wb 8KB
    u16* ldsA  = lds;                   // 2 sub-tiles (k-half), each [128][32]
    u16* ldsWa = lds + 128 * 64;        // 2 sub-tiles, each [64][32]
    u16* ldsWb = lds + 128 * 64 + 64 * 64;

    // staging map: thread t -> (row = t>>2 [+64], chunk = t&3); LDS dest linear
    const int rA = tid >> 2, cA = tid & 3;
    const int tok0 = pt[slot0 + min(rA,      rows - 1)];
    const int tok1 = pt[slot0 + min(rA + 64, rows - 1)];
    const u16* gA0 = xn + (size_t)tok0 * DDIM + cA * 8;
    const u16* gA1 = xn + (size_t)tok1 * DDIM + cA * 8;
    const u16* gWa = wt1a + ((size_t)e * FDIM + f0 + rA) * DDIM + cA * 8;
    const u16* gWb = wt1b + ((size_t)e * FDIM + f0 + rA) * DDIM + cA * 8;
    u16* dA00 = ldsA  + tid * 8;            // k-sub 0, rows 0..63
    u16* dA01 = ldsA  + 2048 + tid * 8;     // k-sub 0, rows 64..127
    u16* dA10 = ldsA  + 4096 + tid * 8;     // k-sub 1, rows 0..63
    u16* dA11 = ldsA  + 6144 + tid * 8;     // k-sub 1, rows 64..127
    u16* dWa0 = ldsWa + tid * 8;            // k-sub 0
    u16* dWa1 = ldsWa + 2048 + tid * 8;     // k-sub 1
    u16* dWb0 = ldsWb + tid * 8;
    u16* dWb1 = ldsWb + 2048 + tid * 8;

    const int wid = tid >> 6, lane = tid & 63;
    const int wm = wid & 1, wn = wid >> 1;        // wave tile: 64m x 32f
    const int ln = lane & 15, q = lane >> 4;

    f32x4 accA[4][2], accB[4][2];
    #pragma unroll
    for (int i = 0; i < 4; i++)
        #pragma unroll
        for (int j = 0; j < 2; j++) {
            accA[i][j] = (f32x4){0.f, 0.f, 0.f, 0.f};
            accB[i][j] = (f32x4){0.f, 0.f, 0.f, 0.f};
        }

    for (int k0 = 0; k0 < DDIM; k0 += 64) {
        __syncthreads();                           // all waves done reading prev tile
        gload_lds16(gA0 + k0,      dA00);
        gload_lds16(gA1 + k0,      dA01);
        gload_lds16(gA0 + k0 + 32, dA10);
        gload_lds16(gA1 + k0 + 32, dA11);
        gload_lds16(gWa + k0,      dWa0);
        gload_lds16(gWa + k0 + 32, dWa1);
        gload_lds16(gWb + k0,      dWb0);
        gload_lds16(gWb + k0 + 32, dWb1);
        __syncthreads();                           // drains vmcnt -> tile ready

        #pragma unroll
        for (int s = 0; s < 2; s++) {
            bf16x8 af[4], ba[2], bb[2];
            #pragma unroll
            for (int i = 0; i < 4; i++)
                af[i] = *(const bf16x8*)(ldsA + s * 4096 + (wm * 64 + i * 16 + ln) * 32 + q * 8);
            #pragma unroll
            for (int j = 0; j < 2; j++) {
                ba[j] = *(const bf16x8*)(ldsWa + s * 2048 + (wn * 32 + j * 16 + ln) * 32 + q * 8);
                bb[j] = *(const bf16x8*)(ldsWb + s * 2048 + (wn * 32 + j * 16 + ln) * 32 + q * 8);
            }
            #pragma unroll
            for (int i = 0; i < 4; i++)
                #pragma unroll
                for (int j = 0; j < 2; j++) {
                    accA[i][j] = __builtin_amdgcn_mfma_f32_16x16x32_bf16(af[i], ba[j], accA[i][j], 0, 0, 0);
                    accB[i][j] = __builtin_amdgcn_mfma_f32_16x16x32_bf16(af[i], bb[j], accB[i][j], 0, 0, 0);
                }
        }
    }

    // epilogue: h = gate_w * silu(a + b1a) * (b + b1b), stored bf16
    #pragma unroll
    for (int i = 0; i < 4; i++) {
        const int mb = wm * 64 + i * 16 + q * 4;
        #pragma unroll
        for (int j = 0; j < 2; j++) {
            const int fg = f0 + wn * 32 + j * 16 + ln;
            const float bav = b1a[e * FDIM + fg];
            const float bbv = b1b[e * FDIM + fg];
            #pragma unroll
            for (int r = 0; r < 4; r++) {
                const int m = mb + r;
                if (m < rows) {
                    const float a = accA[i][j][r] + bav;
                    const float b = accB[i][j][r] + bbv;
                    const float s = a / (1.f + __expf(-a));
                    const float hv = pw[slot0 + m] * s * b;
                    h[(size_t)(slot0 + m) * FDIM + fg] = f2bf(hv);
                }
            }
        }
    }
}

// ---------------- kernel 5T: grouped GEMM2, 128x128 tile, BK=64 + atomics ----------
#define G2_NWG (MAXTILE * (DDIM / 128))    // 136*8 = 1088, %8==0
__global__ __launch_bounds__(256, 2) void k_gemm2_t(
    const u16* __restrict__ h, const int* __restrict__ pt, const float* __restrict__ pw,
    const u16* __restrict__ wt2, const float* __restrict__ b2,
    const int* __restrict__ ntile, const int* __restrict__ tE,
    const int* __restrict__ tS, const int* __restrict__ tR,
    float* __restrict__ out)
{
    const int hw   = blockIdx.y * MAXTILE + blockIdx.x;
    const int work = (hw & 7) * (G2_NWG / 8) + (hw >> 3);
    const int bx   = work % MAXTILE;
    const int n0   = (work / MAXTILE) * 128;

    if (bx >= *ntile) return;
    const int e = tE[bx], slot0 = tS[bx], rows = tR[bx];
    const int tid = threadIdx.x;

    __shared__ u16 lds[2 * 128 * 64];             // A 16KB | W 16KB
    u16* ldsA = lds;                    // 2 sub-tiles, each [128][32]
    u16* ldsW = lds + 128 * 64;         // 2 sub-tiles, each [128][32]

    const int rA = tid >> 2, cA = tid & 3;
    const int r0c = min(rA,      rows - 1);
    const int r1c = min(rA + 64, rows - 1);
    const u16* gA0 = h + (size_t)(slot0 + r0c) * FDIM + cA * 8;
    const u16* gA1 = h + (size_t)(slot0 + r1c) * FDIM + cA * 8;
    const u16* gW0 = wt2 + ((size_t)e * DDIM + n0 + rA)      * FDIM + cA * 8;
    const u16* gW1 = wt2 + ((size_t)e * DDIM + n0 + rA + 64) * FDIM + cA * 8;
    u16* dA00 = ldsA + tid * 8;            // k-sub 0, rows 0..63
    u16* dA01 = ldsA + 2048 + tid * 8;     // k-sub 0, rows 64..127
    u16* dA10 = ldsA + 4096 + tid * 8;     // k-sub 1, rows 0..63
    u16* dA11 = ldsA + 6144 + tid * 8;     // k-sub 1, rows 64..127
    u16* dW00 = ldsW + tid * 8;
    u16* dW01 = ldsW + 2048 + tid * 8;
    u16* dW10 = ldsW + 4096 + tid * 8;
    u16* dW11 = ldsW + 6144 + tid * 8;

    const int wid = tid >> 6, lane = tid & 63;
    const int wm = wid & 1, wn = wid >> 1;        // wave tile: 64m x 64n
    const int ln = lane & 15, q = lane >> 4;

    f32x4 acc[4][4];
    #pragma unroll
    for (int i = 0; i < 4; i++)
        #pragma unroll
        for (int j = 0; j < 4; j++) acc[i][j] = (f32x4){0.f, 0.f, 0.f, 0.f};

    for (int k0 = 0; k0 < FDIM; k0 += 64) {
        __syncthreads();
        gload_lds16(gA0 + k0,      dA00);
        gload_lds16(gA1 + k0,      dA01);
        gload_lds16(gA0 + k0 + 32, dA10);
        gload_lds16(gA1 + k0 + 32, dA11);
        gload_lds16(gW0 + k0,      dW00);
        gload_lds16(gW1 + k0,      dW01);
        gload_lds16(gW0 + k0 + 32, dW10);
        gload_lds16(gW1 + k0 + 32, dW11);
        __syncthreads();

        #pragma unroll
        for (int s = 0; s < 2; s++) {
            bf16x8 af[4], bf[4];
            #pragma unroll
            for (int i = 0; i < 4; i++)
                af[i] = *(const bf16x8*)(ldsA + s * 4096 + (wm * 64 + i * 16 + ln) * 32 + q * 8);
            #pragma unroll
            for (int j = 0; j < 4; j++)
                bf[j] = *(const bf16x8*)(ldsW + s * 4096 + (wn * 64 + j * 16 + ln) * 32 + q * 8);
            #pragma unroll
            for (int i = 0; i < 4; i++)
                #pragma unroll
                for (int j = 0; j < 4; j++)
                    acc[i][j] = __builtin_amdgcn_mfma_f32_16x16x32_bf16(af[i], bf[j], acc[i][j], 0, 0, 0);
        }
    }

    #pragma unroll
    for (int i = 0; i < 4; i++) {
        const int mb = wm * 64 + i * 16 + q * 4;
        #pragma unroll
        for (int j = 0; j < 4; j++) {
            const int d = n0 + wn * 64 + j * 16 + ln;
            const float b2v = b2[e * DDIM + d];
            #pragma unroll
            for (int r = 0; r < 4; r++) {
                const int m = mb + r;
                if (m < rows) {
                    const int slot = slot0 + m;
                    const int tok = pt[slot];
                    const float val = acc[i][j][r] + pw[slot] * b2v;
                    atomicAdd(out + (size_t)tok * DDIM + d, val);
                }
            }
        }
    }
}

// ================= FALLBACK PATH (verified baseline, unchanged) =================

__global__ __launch_bounds__(256, 2) void k_gemm1(
    const u16* __restrict__ xn, const int* __restrict__ pt, const float* __restrict__ pw,
    const float* __restrict__ W1a, const float* __restrict__ b1a,
    const float* __restrict__ W1b, const float* __restrict__ b1b,
    const int* __restrict__ ntile, const int* __restrict__ tE,
    const int* __restrict__ tS, const int* __restrict__ tR,
    u16* __restrict__ h)
{
    const int bx = blockIdx.x;
    if (bx >= *ntile) return;
    const int e = tE[bx], slot0 = tS[bx], rows = tR[bx];
    const int f0 = blockIdx.y * 128;
    const int tid = threadIdx.x;

    __shared__ u16 lds[3 * 128 * 40];
    u16* ldsA  = lds;
    u16* ldsWa = lds + 128 * 40;
    u16* ldsWb = lds + 2 * 128 * 40;

    const int ar = tid >> 1, ah = tid & 1;
    const int tok = pt[slot0 + min(ar, rows - 1)];
    const u16* aptr = xn + (size_t)tok * DDIM + ah * 16;

    const int fq = tid & 31, dq = tid >> 5;
    const float* wa_base = W1a + (size_t)e * DDIM * FDIM + (f0 + fq * 4);
    const float* wb_base = W1b + (size_t)e * DDIM * FDIM + (f0 + fq * 4);

    const int wid = tid >> 6, lane = tid & 63;
    const int wm = wid & 1, wn = wid >> 1;
    const int ln = lane & 15, q = lane >> 4;

    f32x4 accA[4][4], accB[4][4];
    #pragma unroll
    for (int i = 0; i < 4; i++)
        #pragma unroll
        for (int j = 0; j < 4; j++) {
            accA[i][j] = (f32x4){0.f, 0.f, 0.f, 0.f};
            accB[i][j] = (f32x4){0.f, 0.f, 0.f, 0.f};
        }

    for (int k0 = 0; k0 < DDIM; k0 += 32) {
        const uint4 av0 = *(const uint4*)(aptr + k0);
        const uint4 av1 = *(const uint4*)(aptr + k0 + 8);
        float4 wa[4], wb[4];
        #pragma unroll
        for (int i = 0; i < 4; i++) {
            wa[i] = *(const float4*)(wa_base + (size_t)(k0 + dq * 4 + i) * FDIM);
            wb[i] = *(const float4*)(wb_base + (size_t)(k0 + dq * 4 + i) * FDIM);
        }
        __syncthreads();
        *(uint4*)(ldsA + ar * 40 + ah * 16)     = av0;
        *(uint4*)(ldsA + ar * 40 + ah * 16 + 8) = av1;
        #pragma unroll
        for (int j = 0; j < 4; j++) {
            ushort4 pa, pb;
            pa.x = f2bf(((const float*)&wa[0])[j]); pa.y = f2bf(((const float*)&wa[1])[j]);
            pa.z = f2bf(((const float*)&wa[2])[j]); pa.w = f2bf(((const float*)&wa[3])[j]);
            pb.x = f2bf(((const float*)&wb[0])[j]); pb.y = f2bf(((const float*)&wb[1])[j]);
            pb.z = f2bf(((const float*)&wb[2])[j]); pb.w = f2bf(((const float*)&wb[3])[j]);
            *(ushort4*)(ldsWa + (fq * 4 + j) * 40 + dq * 4) = pa;
            *(ushort4*)(ldsWb + (fq * 4 + j) * 40 + dq * 4) = pb;
        }
        __syncthreads();
        bf16x8 af[4], ba[4], bb[4];
        #pragma unroll
        for (int i = 0; i < 4; i++)
            af[i] = *(const bf16x8*)(ldsA + (wm * 64 + i * 16 + ln) * 40 + q * 8);
        #pragma unroll
        for (int j = 0; j < 4; j++) {
            ba[j] = *(const bf16x8*)(ldsWa + (wn * 64 + j * 16 + ln) * 40 + q * 8);
            bb[j] = *(const bf16x8*)(ldsWb + (wn * 64 + j * 16 + ln) * 40 + q * 8);
        }
        #pragma unroll
        for (int i = 0; i < 4; i++)
            #pragma unroll
            for (int j = 0; j < 4; j++) {
                accA[i][j] = __builtin_amdgcn_mfma_f32_16x16x32_bf16(af[i], ba[j], accA[i][j], 0, 0, 0);
                accB[i][j] = __builtin_amdgcn_mfma_f32_16x16x32_bf16(af[i], bb[j], accB[i][j], 0, 0, 0);
            }
    }

    #pragma unroll
    for (int i = 0; i < 4; i++) {
        const int mb = wm * 64 + i * 16 + q * 4;
        #pragma unroll
        for (int j = 0; j < 4; j++) {
            const int fg = f0 + wn * 64 + j * 16 + ln;
            const float bav = b1a[e * FDIM + fg];
            const float bbv = b1b[e * FDIM + fg];
            #pragma unroll
            for (int r = 0; r < 4; r++) {
                const int m = mb + r;
                if (m < rows) {
                    const float a = accA[i][j][r] + bav;
                    const float b = accB[i][j][r] + bbv;
                    const float s = a / (1.f + __expf(-a));
                    const float hv = pw[slot0 + m] * s * b;
                    h[(size_t)(slot0 + m) * FDIM + fg] = f2bf(hv);
                }
            }
        }
    }
}

__global__ __launch_bounds__(256, 2) void k_gemm2(
    const u16* __restrict__ h, const int* __restrict__ pt, const float* __restrict__ pw,
    const float* __restrict__ W2, const float* __restrict__ b2,
    const int* __restrict__ ntile, const int* __restrict__ tE,
    const int* __restrict__ tS, const int* __restrict__ tR,
    float* __restrict__ out)
{
    const int bx = blockIdx.x;
    if (bx >= *ntile) return;
    const int e = tE[bx], slot0 = tS[bx], rows = tR[bx];
    const int n0 = blockIdx.y * 128;
    const int tid = threadIdx.x;

    __shared__ u16 lds[2 * 128 * 40];
    u16* ldsA = lds;
    u16* ldsW = lds + 128 * 40;

    const int ar = tid >> 1, ah = tid & 1;
    const int arc = min(ar, rows - 1);
    const u16* aptr = h + (size_t)(slot0 + arc) * FDIM + ah * 16;

    const int fq = tid & 31, dq = tid >> 5;
    const float* w_base = W2 + (size_t)e * FDIM * DDIM + (n0 + fq * 4);

    const int wid = tid >> 6, lane = tid & 63;
    const int wm = wid & 1, wn = wid >> 1;
    const int ln = lane & 15, q = lane >> 4;

    f32x4 acc[4][4];
    #pragma unroll
    for (int i = 0; i < 4; i++)
        #pragma unroll
        for (int j = 0; j < 4; j++) acc[i][j] = (f32x4){0.f, 0.f, 0.f, 0.f};

    for (int k0 = 0; k0 < FDIM; k0 += 32) {
        const uint4 av0 = *(const uint4*)(aptr + k0);
        const uint4 av1 = *(const uint4*)(aptr + k0 + 8);
        float4 wv[4];
        #pragma unroll
        for (int i = 0; i < 4; i++)
            wv[i] = *(const float4*)(w_base + (size_t)(k0 + dq * 4 + i) * DDIM);
        __syncthreads();
        *(uint4*)(ldsA + ar * 40 + ah * 16)     = av0;
        *(uint4*)(ldsA + ar * 40 + ah * 16 + 8) = av1;
        #pragma unroll
        for (int j = 0; j < 4; j++) {
            ushort4 p;
            p.x = f2bf(((const float*)&wv[0])[j]); p.y = f2bf(((const float*)&wv[1])[j]);
            p.z = f2bf(((const float*)&wv[2])[j]); p.w = f2bf(((const float*)&wv[3])[j]);
            *(ushort4*)(ldsW + (fq * 4 + j) * 40 + dq * 4) = p;
        }
        __syncthreads();
        bf16x8 af[4], bf[4];
        #pragma unroll
        for (int i = 0; i < 4; i++)
            af[i] = *(const bf16x8*)(ldsA + (wm * 64 + i * 16 + ln) * 40 + q * 8);
        #pragma unroll
        for (int j = 0; j < 4; j++)
            bf[j] = *(const bf16x8*)(ldsW + (wn * 64 + j * 16 + ln) * 40 + q * 8);
        #pragma unroll
        for (int i = 0; i < 4; i++)
            #pragma unroll
            for (int j = 0; j < 4; j++)
                acc[i][j] = __builtin_amdgcn_mfma_f32_16x16x32_bf16(af[i], bf[j], acc[i][j], 0, 0, 0);
    }

    #pragma unroll
    for (int i = 0; i < 4; i++) {
        const int mb = wm * 64 + i * 16 + q * 4;
        #pragma unroll
        for (int j = 0; j < 4; j++) {
            const int d = n0 + wn * 64 + j * 16 + ln;
            const float b2v = b2[e * DDIM + d];
            #pragma unroll
            for (int r = 0; r < 4; r++) {
                const int m = mb + r;
                if (m < rows) {
                    const int slot = slot0 + m;
                    const int tok = pt[slot];
                    const float val = acc[i][j][r] + pw[slot] * b2v;
                    atomicAdd(out + (size_t)tok * DDIM + d, val);
                }
            }
        }
    }
}

// ---------------- launch ----------------
extern "C" void kernel_launch(void* const* d_in, const int* in_sizes, int n_in,
                              void* d_out, int out_size, void* d_ws, size_t ws_size,
                              hipStream_t stream)
{
    (void)in_sizes; (void)n_in; (void)out_size;
    const float* x   = (const float*)d_in[0];
    const float* lnw = (const float*)d_in[1];
    const float* Wg  = (const float*)d_in[2];
    const float* bg  = (const float*)d_in[3];
    const float* W1a = (const float*)d_in[4];
    const float* b1a = (const float*)d_in[5];
    const float* W1b = (const float*)d_in[6];
    const float* b1b = (const float*)d_in[7];
    const float* W2  = (const float*)d_in[8];
    const float* b2  = (const float*)d_in[9];
    float* out = (float*)d_out;
    char* ws = (char*)d_ws;

    u16*   xn     = (u16*)(ws + XN_OFF);
    u16*   h      = (u16*)(ws + H_OFF);
    int*   counts = (int*)(ws + CNT_OFF);
    int*   offs   = (int*)(ws + OFF_OFF);
    int*   ntile  = (int*)(ws + NT_OFF);
    int*   tE     = (int*)(ws + TE_OFF);
    int*   tS     = (int*)(ws + TS_OFF);
    int*   tR     = (int*)(ws + TR_OFF);
    int*   ek     = (int*)(ws + EK_OFF);
    int*   rk     = (int*)(ws + RK_OFF);
    float* wk     = (float*)(ws + WK_OFF);
    int*   pt     = (int*)(ws + PT_OFF);
    float* pw     = (float*)(ws + PW_OFF);

    hipMemsetAsync(counts, 0, 32, stream);
    hipMemsetAsync(out, 0, (size_t)T_TOK * DDIM * sizeof(float), stream);

    const bool big = (ws_size >= WS_BIG);

    if (big) {
        u16* wt1a = (u16*)(ws + WT1A_OFF);
        u16* wt1b = (u16*)(ws + WT1B_OFF);
        u16* wt2  = (u16*)(ws + WT2_OFF);

        // weight transpose+convert: W1 [E][D][F]->[E][F][D], W2 [E][F][D]->[E][D][F]
        k_transpose<<<dim3(FDIM / 64, DDIM / 64, NEXP), 256, 0, stream>>>(W1a, wt1a, DDIM, FDIM);
        k_transpose<<<dim3(FDIM / 64, DDIM / 64, NEXP), 256, 0, stream>>>(W1b, wt1b, DDIM, FDIM);
        k_transpose<<<dim3(DDIM / 64, FDIM / 64, NEXP), 256, 0, stream>>>(W2,  wt2,  FDIM, DDIM);

        k_rms_gate<<<T_TOK, 256, 0, stream>>>(x, lnw, Wg, bg, xn, counts, ek, rk, wk);
        k_plan<<<1, 1, 0, stream>>>(counts, offs, ntile, tE, tS, tR);
        k_scatter<<<NSLOT / 256, 256, 0, stream>>>(ek, rk, wk, offs, pt, pw);

        dim3 g1(MAXTILE, FDIM / 64);
        k_gemm1_t<<<g1, 256, 0, stream>>>(xn, pt, pw, wt1a, b1a, wt1b, b1b,
                                          ntile, tE, tS, tR, h);
        dim3 g2(MAXTILE, DDIM / 128);
        k_gemm2_t<<<g2, 256, 0, stream>>>(h, pt, pw, wt2, b2,
                                          ntile, tE, tS, tR, out);
    } else {
        // fallback: verified baseline path (workspace too small for bf16 W^T)
        k_rms_gate<<<T_TOK, 256, 0, stream>>>(x, lnw, Wg, bg, xn, counts, ek, rk, wk);
        k_plan<<<1, 1, 0, stream>>>(counts, offs, ntile, tE, tS, tR);
        k_scatter<<<NSLOT / 256, 256, 0, stream>>>(ek, rk, wk, offs, pt, pw);

        dim3 g1(MAXTILE, FDIM / 128);
        k_gemm1<<<g1, 256, 0, stream>>>(xn, pt, pw, W1a, b1a, W1b, b1b,
                                        ntile, tE, tS, tR, h);
        dim3 g2(MAXTILE, DDIM / 128);
        k_gemm2<<<g2, 256, 0, stream>>>(h, pt, pw, W2, b2,
                                        ntile, tE, tS, tR, out);
    }
}